// Round 7
// baseline (5379.867 us; speedup 1.0000x reference)
//
#include <hip/hip_runtime.h>
#include <hip/hip_bf16.h>

// LSTM: B=64, D=32, H=512, T=1024. gates = [h,x] @ [W_hh;W_ih]^T + b_ih + b_hh
// Round 7: drain-clean release + barrier-lean loop.
//  - h ring: one 128B line per producing WAVE per plane (R6 layout, validated).
//  - flags: one 128B line per producing WAVE, value-coded (>= t), ring-4.
//    Producer wave: pack/store h (interleaved in gate loop) -> vmcnt(0)
//    (ONLY h stores outstanding) -> own flag. No producer-side barrier.
//  - projection partials buffered in LDS (projsh[4][16][64]), flushed every
//    64 steps as coalesced NT bursts -> no per-step HBM store acks in drain,
//    no partial-line write amplification.
//  - consumer: wave0 polls 128 flag lines (2/lane), one __syncthreads.
// 128 blocks (4 batch-groups x 32 slices of 16 units), 256 thr (4 waves).

typedef unsigned short ushort_t;
typedef unsigned int   uint_t;
typedef unsigned long long u64_t;
typedef __attribute__((ext_vector_type(8))) short bf16x8;
typedef __attribute__((ext_vector_type(4))) float f32x4;

#define T_STEPS 1024
#define HID     512
#define KDIM    544   // 512 h + 32 x
#define NBLK    128   // 4 groups * 32 slices
#define NTHR    256

__device__ inline ushort_t f2bf(float x) {
    __hip_bfloat16 h = __float2bfloat16(x);
    return *(ushort_t*)&h;
}
__device__ inline float bf2f(ushort_t u) {
    __hip_bfloat16 h = *(__hip_bfloat16*)&u;
    return __bfloat162float(h);
}

__device__ inline f32x4 MFMA(bf16x8 a, bf16x8 b, f32x4 c) {
    return __builtin_amdgcn_mfma_f32_16x16x32_bf16(a, b, c, 0, 0, 0);
}

// is_tanh: tanh(v)=(1-e)/(1+e), e=2^(-2.885*v); sigmoid(v)=1/(1+e), e=2^(-1.4427*v)
__device__ inline float act_gate(float v, int is_tanh) {
    float vc = fminf(fmaxf(v, -43.f), 43.f);
    float kk = is_tanh ? -2.88539008f : -1.44269504f;
    float e  = __builtin_exp2f(vc * kk);
    float num = is_tanh ? (1.f - e) : 1.f;
    return num * __builtin_amdgcn_rcpf(1.f + e);
}

__device__ inline float sel4(int i, float a, float b, float c, float d) {
    return (i == 0) ? a : (i == 1) ? b : (i == 2) ? c : d;
}

// ---------- prep kernels ----------

__global__ void k_init(uint_t* flags, uint_t* hhi32, uint_t* hlo32) {
    int i = blockIdx.x * 256 + threadIdx.x;      // grid 256x256 = 65536
    flags[i] = 0;                                // 4 rings*4 g*128 wg*32 pad u32
    if (i < 32768) { hhi32[i] = 0; hlo32[i] = 0; } // h ring, both slots/planes
}

__global__ void k_wcat(const float* __restrict__ wih, const float* __restrict__ whh,
                       ushort_t* __restrict__ wh, ushort_t* __restrict__ wl) {
    int r = blockIdx.x;                          // 2048 gate rows
    for (int k = threadIdx.x; k < KDIM; k += 256) {
        float w = (k < 512) ? whh[r * 512 + k] : wih[r * 32 + (k - 512)];
        ushort_t hh = f2bf(w);
        ushort_t ll = f2bf(w - bf2f(hh));
        wh[r * KDIM + k] = hh;
        wl[r * KDIM + k] = ll;
    }
}

// input (B=64, D=32, T=1024) fp32 -> xbuf[t][b][d] bf16 hi/lo
__global__ void k_xbuf(const float* __restrict__ in,
                       ushort_t* __restrict__ xh, ushort_t* __restrict__ xl) {
    __shared__ float tile[64][65];
    int bp = blockIdx.x >> 4;                    // batch pair 0..31
    int tt = blockIdx.x & 15;                    // t tile 0..15
    int t0 = tt * 64;
    int wv = threadIdx.x >> 6, l = threadIdx.x & 63;
    for (int r = wv * 16; r < wv * 16 + 16; r++) {
        int b = bp * 2 + (r >> 5), d = r & 31;
        tile[r][l] = in[(b * 32 + d) * 1024 + t0 + l];
    }
    __syncthreads();
    for (int i = 0; i < 16; i++) {
        int tl = wv * 16 + i;
        float v = tile[l][tl];
        ushort_t hh = f2bf(v);
        ushort_t ll = f2bf(v - bf2f(hh));
        int o = (t0 + tl) * 2048 + bp * 64 + l;  // = t*64*32 + b*32 + d
        xh[o] = hh;
        xl[o] = ll;
    }
}

// out[b][t] = conv_b + sum_s part[(g*32+s)*16 + bl][t]   (b = g*16+bl)
__global__ void k_reduce(const float* __restrict__ part, float* __restrict__ out,
                         const float* __restrict__ cvb) {
    int b = blockIdx.x >> 2;                     // 0..63
    int t = (blockIdx.x & 3) * 256 + threadIdx.x;
    int g = b >> 4, bl = b & 15;
    const float* p = part + ((size_t)(g * 32 * 16 + bl)) * 1024 + t;
    float sum = 0.f;
    #pragma unroll
    for (int s = 0; s < 32; s++) sum += p[(size_t)s * 16 * 1024];
    out[b * 1024 + t] = sum + cvb[0];
}

// ---------- main recurrent kernel ----------

__global__ __launch_bounds__(NTHR, 1) void k_lstm(
    const ushort_t* __restrict__ wh, const ushort_t* __restrict__ wlo,
    const ushort_t* __restrict__ xh, const ushort_t* __restrict__ xl,
    u64_t* h64hi, u64_t* h64lo, uint_t* flags,
    const float* __restrict__ bih, const float* __restrict__ bhh,
    const float* __restrict__ convw, float* __restrict__ part)
{
    const int tid = threadIdx.x;
    const int w   = tid >> 6;          // wave 0..3 (unit nibble)
    const int l   = tid & 63;
    const int g   = blockIdx.x >> 5;   // batch group 0..3
    const int s   = blockIdx.x & 31;   // hidden slice 0..31 (16 units each)
    const int n   = l & 15;            // B-tile row within wave
    const int q   = l >> 4;            // quad
    const int gtn = n >> 2;            // gate 0..3 (i,f,g,o)
    const int u   = n & 3;             // unit within wave
    const int j   = s * 16 + w * 4 + u;// hidden unit 0..511
    const int row = gtn * HID + j;     // gate row 0..2047
    const int b0  = g * 16;
    const int wg  = s * 4 + w;         // producing-wave id in group, 0..127

    __shared__ ushort_t blo[64][552];  // W_lo slice, padded stride
    __shared__ float projsh[4][16][64];// per-wave projection partials, 64-step

    // stage W_lo to LDS: 64 rows x 544, 8-elem (16B) chunks
    for (int e = tid; e < 64 * 68; e += NTHR) {
        int rl = e / 68, ch = e - rl * 68;
        int ww = rl >> 4, nn = rl & 15;
        int gg = nn >> 2, uu = nn & 3;
        int rr = gg * HID + s * 16 + ww * 4 + uu;
        *(bf16x8*)&blo[rl][ch * 8] = *(const bf16x8*)(wlo + rr * KDIM + ch * 8);
    }

    // W_hi fragments in registers: 17 K-chunks
    bf16x8 Bh[17];
    #pragma unroll
    for (int c = 0; c < 17; c++)
        Bh[c] = *(const bf16x8*)(wh + row * KDIM + c * 32 + q * 8);

    const float bias = bih[row] + bhh[row];
    const float cw   = convw[j];
    float cst[4] = {0.f, 0.f, 0.f, 0.f};

    __syncthreads();
    const int rl16 = w * 16 + n;

    union frag { u64_t d[2]; bf16x8 v; };

    for (int t = 0; t < T_STEPS; t++) {
        frag Ah[17], Al[17];
        // x fragment: no dependence on flags -> prefetch into regs before poll
        {
            int xo = (t * 64 + b0 + n) * 32 + q * 8;
            Ah[16].v = *(const bf16x8*)(xh + xo);
            Al[16].v = *(const bf16x8*)(xl + xo);
        }

        if (t > 0) {
            if (w == 0) {
                // 128 per-wave flag lines; lane polls lines 2l, 2l+1; value>=t
                const uint_t* fb = flags +
                    (size_t)((((t - 1) & 3) * 4 + g) * 128) * 32;
                for (;;) {
                    uint_t f0 = __hip_atomic_load(fb + (2 * l) * 32,
                                  __ATOMIC_RELAXED, __HIP_MEMORY_SCOPE_AGENT);
                    uint_t f1 = __hip_atomic_load(fb + (2 * l + 1) * 32,
                                  __ATOMIC_RELAXED, __HIP_MEMORY_SCOPE_AGENT);
                    if (__all(f0 >= (uint_t)t && f1 >= (uint_t)t)) break;
                }
            }
            __syncthreads();
        }

        // h fragments: relaxed-agent u64 bypass loads straight into fragment
        // registers. h64[slot][g][wgp][m]: chunk c quad q row n ->
        // wgp = c*8+q*2 (units c*32+q*8..+3) and wgp+1 (next 4 units).
        {
            const u64_t* bp_ = h64hi + (size_t)(((t & 1) * 4 + g) * 128) * 16;
            const u64_t* bl_ = h64lo + (size_t)(((t & 1) * 4 + g) * 128) * 16;
            #pragma unroll
            for (int c = 0; c < 16; c++) {
                int o = (c * 8 + q * 2) * 16 + n;
                Ah[c].d[0] = __hip_atomic_load(bp_ + o,      __ATOMIC_RELAXED,
                                               __HIP_MEMORY_SCOPE_AGENT);
                Ah[c].d[1] = __hip_atomic_load(bp_ + o + 16, __ATOMIC_RELAXED,
                                               __HIP_MEMORY_SCOPE_AGENT);
                Al[c].d[0] = __hip_atomic_load(bl_ + o,      __ATOMIC_RELAXED,
                                               __HIP_MEMORY_SCOPE_AGENT);
                Al[c].d[1] = __hip_atomic_load(bl_ + o + 16, __ATOMIC_RELAXED,
                                               __HIP_MEMORY_SCOPE_AGENT);
            }
        }

        f32x4 a0 = {0,0,0,0}, a1 = {0,0,0,0}, a2 = {0,0,0,0},
              a3 = {0,0,0,0}, a4 = {0,0,0,0}, a5 = {0,0,0,0};
        #pragma unroll
        for (int c = 0; c < 17; c++) {
            bf16x8 bl_ = *(const bf16x8*)&blo[rl16][c * 32 + q * 8];
            if (c & 1) {
                a1 = MFMA(Ah[c].v, Bh[c], a1);
                a3 = MFMA(Ah[c].v, bl_,   a3);
                a5 = MFMA(Al[c].v, Bh[c], a5);
            } else {
                a0 = MFMA(Ah[c].v, Bh[c], a0);
                a2 = MFMA(Ah[c].v, bl_,   a2);
                a4 = MFMA(Al[c].v, Bh[c], a4);
            }
        }
        f32x4 D = (a0 + a1) + (a2 + a3) + (a4 + a5);

        // epilogue: lane holds gate row n for batches m=q*4+r.
        // pack+store interleaved per r so the h stores issue early.
        u64_t* dh = h64hi + (size_t)((((t + 1) & 1) * 4 + g) * 128 + wg) * 16;
        u64_t* dl = h64lo + (size_t)((((t + 1) & 1) * 4 + g) * 128 + wg) * 16;
        float pr[4];
        #pragma unroll
        for (int r = 0; r < 4; r++) {
            float v   = D[r] + bias;
            float act = act_gate(v, gtn == 2);
            float v4  = __shfl_xor(act, 4);
            float v8  = __shfl_xor(act, 8);
            float v12 = __shfl_xor(v4, 8);
            // gate G lives at arr[gtn ^ G]; arr = {act, v4, v8, v12}
            float iv = sel4(gtn,     act, v4, v8, v12);
            float fv = sel4(gtn ^ 1, act, v4, v8, v12);
            float gv = sel4(gtn ^ 2, act, v4, v8, v12);
            float ov = sel4(gtn ^ 3, act, v4, v8, v12);
            float cc = fv * cst[r] + iv * gv;
            cst[r] = cc;
            float th = act_gate(cc, 1);
            float h  = ov * th;
            pr[r] = cw * h;
            ushort_t hb = f2bf(h);
            uint_t hv = (uint_t)hb;
            uint_t lv = (uint_t)f2bf(h - bf2f(hb));
            uint_t h1 = (uint_t)__shfl_xor((int)hv, 1);
            uint_t l1 = (uint_t)__shfl_xor((int)lv, 1);
            uint_t hp = hv | (h1 << 16);          // [u, u^1] valid on even u
            uint_t lp = lv | (l1 << 16);
            uint_t h2 = (uint_t)__shfl_xor((int)hp, 2);
            uint_t l2 = (uint_t)__shfl_xor((int)lp, 2);
            if (n == 0) {
                __hip_atomic_store(dh + q * 4 + r,
                    (u64_t)hp | ((u64_t)h2 << 32),
                    __ATOMIC_RELAXED, __HIP_MEMORY_SCOPE_AGENT);
                __hip_atomic_store(dl + q * 4 + r,
                    (u64_t)lp | ((u64_t)l2 << 32),
                    __ATOMIC_RELAXED, __HIP_MEMORY_SCOPE_AGENT);
            }
        }

        // release: ONLY the 8 h stores are outstanding here -> one L3 ack,
        // then this wave's own flag line (value t+1, ring t&3).
        __builtin_amdgcn_s_waitcnt(0x0F70);   // vmcnt(0)
        if (l == 0)
            __hip_atomic_store(
                flags + (size_t)(((t & 3) * 4 + g) * 128 + wg) * 32,
                (uint_t)(t + 1),
                __ATOMIC_RELAXED, __HIP_MEMORY_SCOPE_AGENT);

        // projection partial (off critical path): sum this wave's 4 units
        #pragma unroll
        for (int r = 0; r < 4; r++) {
            pr[r] += __shfl_xor(pr[r], 1);
            pr[r] += __shfl_xor(pr[r], 2);
            if (n == 0) projsh[w][q * 4 + r][t & 63] = pr[r];
        }

        // flush projection partials every 64 steps (coalesced NT bursts)
        if ((t & 63) == 63) {
            __syncthreads();
            float* dst = part + (size_t)((g * 32 + s) * 16) * 1024 + (t - 63);
            for (int i = tid; i < 1024; i += NTHR) {
                int b = i >> 6, tl = i & 63;
                float v = (projsh[0][b][tl] + projsh[1][b][tl]) +
                          (projsh[2][b][tl] + projsh[3][b][tl]);
                __builtin_nontemporal_store(v, dst + (size_t)b * 1024 + tl);
            }
            __syncthreads();
        }
    }
}

extern "C" void kernel_launch(void* const* d_in, const int* in_sizes, int n_in,
                              void* d_out, int out_size, void* d_ws, size_t ws_size,
                              hipStream_t stream) {
    const float* in  = (const float*)d_in[0];
    const float* Wih = (const float*)d_in[1];
    const float* Whh = (const float*)d_in[2];
    const float* bih = (const float*)d_in[3];
    const float* bhh = (const float*)d_in[4];
    const float* cvw = (const float*)d_in[5];
    const float* cvb = (const float*)d_in[6];
    float* out = (float*)d_out;

    char* ws = (char*)d_ws;
    ushort_t* wh  = (ushort_t*)ws; ws += (size_t)2048 * KDIM * 2;      // 2,228,224
    ushort_t* wl  = (ushort_t*)ws; ws += (size_t)2048 * KDIM * 2;
    ushort_t* xh  = (ushort_t*)ws; ws += (size_t)1024 * 64 * 32 * 2;   // 4,194,304
    ushort_t* xl  = (ushort_t*)ws; ws += (size_t)1024 * 64 * 32 * 2;
    u64_t*    hhi = (u64_t*)ws;    ws += (size_t)2 * 4 * 128 * 16 * 8; // 131,072
    u64_t*    hlo = (u64_t*)ws;    ws += (size_t)2 * 4 * 128 * 16 * 8;
    uint_t*   fl  = (uint_t*)ws;   ws += (size_t)4 * 4 * 128 * 32 * 4; // 262,144
    float*    pp  = (float*)ws;    ws += (size_t)128 * 16 * 1024 * 4;  // 8,388,608
    // total ~21.8 MB of ws

    k_init<<<256, 256, 0, stream>>>(fl, (uint_t*)hhi, (uint_t*)hlo);
    k_wcat<<<2048, 256, 0, stream>>>(Wih, Whh, wh, wl);
    k_xbuf<<<512, 256, 0, stream>>>(in, xh, xl);
    k_lstm<<<NBLK, NTHR, 0, stream>>>(wh, wl, xh, xl, hhi, hlo, fl,
                                      bih, bhh, cvw, pp);
    k_reduce<<<256, 256, 0, stream>>>(pp, out, cvb);
}

// Round 8
// 4428.894 us; speedup vs baseline: 1.2147x; 1.2147x over previous
//
#include <hip/hip_runtime.h>
#include <hip/hip_bf16.h>

// LSTM: B=64, D=32, H=512, T=1024. gates = [h,x] @ [W_hh;W_ih]^T + b_ih + b_hh
// Round 8: L3-traffic diet.
//  - h ring (R6 layout) + per-wave flags (R7) unchanged.
//  - h A-tile staged ONCE per block via LDS: 16 coalesced atomic u64 loads
//    per lane (2KB/instr), ds_write relayout -> every fragment is a
//    contiguous 16B ds_read_b128 (bank-balanced). 16 -> 4 MB/step L3 traffic.
//  - W_lo in LDS but fragment-contiguous (bloF[c][q][rl]) -> no conflicts.
//  - poll distributed across all 4 waves (1 line/lane, 32 lanes/wave),
//    two barriers/step (poll + staging).
// 128 blocks (4 batch-groups x 32 slices of 16 units), 256 thr (4 waves).

typedef unsigned short ushort_t;
typedef unsigned int   uint_t;
typedef unsigned long long u64_t;
typedef __attribute__((ext_vector_type(8))) short bf16x8;
typedef __attribute__((ext_vector_type(4))) float f32x4;

#define T_STEPS 1024
#define HID     512
#define KDIM    544   // 512 h + 32 x
#define NBLK    128   // 4 groups * 32 slices
#define NTHR    256

__device__ inline ushort_t f2bf(float x) {
    __hip_bfloat16 h = __float2bfloat16(x);
    return *(ushort_t*)&h;
}
__device__ inline float bf2f(ushort_t u) {
    __hip_bfloat16 h = *(__hip_bfloat16*)&u;
    return __bfloat162float(h);
}

__device__ inline f32x4 MFMA(bf16x8 a, bf16x8 b, f32x4 c) {
    return __builtin_amdgcn_mfma_f32_16x16x32_bf16(a, b, c, 0, 0, 0);
}

// is_tanh: tanh(v)=(1-e)/(1+e), e=2^(-2.885*v); sigmoid(v)=1/(1+e), e=2^(-1.4427*v)
__device__ inline float act_gate(float v, int is_tanh) {
    float vc = fminf(fmaxf(v, -43.f), 43.f);
    float kk = is_tanh ? -2.88539008f : -1.44269504f;
    float e  = __builtin_exp2f(vc * kk);
    float num = is_tanh ? (1.f - e) : 1.f;
    return num * __builtin_amdgcn_rcpf(1.f + e);
}

__device__ inline float sel4(int i, float a, float b, float c, float d) {
    return (i == 0) ? a : (i == 1) ? b : (i == 2) ? c : d;
}

// ---------- prep kernels ----------

__global__ void k_init(uint_t* flags, uint_t* hhi32, uint_t* hlo32) {
    int i = blockIdx.x * 256 + threadIdx.x;      // grid 256x256 = 65536
    flags[i] = 0;                                // 4 rings*4 g*128 wg*32 pad u32
    if (i < 32768) { hhi32[i] = 0; hlo32[i] = 0; } // h ring, both slots/planes
}

__global__ void k_wcat(const float* __restrict__ wih, const float* __restrict__ whh,
                       ushort_t* __restrict__ wh, ushort_t* __restrict__ wl) {
    int r = blockIdx.x;                          // 2048 gate rows
    for (int k = threadIdx.x; k < KDIM; k += 256) {
        float w = (k < 512) ? whh[r * 512 + k] : wih[r * 32 + (k - 512)];
        ushort_t hh = f2bf(w);
        ushort_t ll = f2bf(w - bf2f(hh));
        wh[r * KDIM + k] = hh;
        wl[r * KDIM + k] = ll;
    }
}

// input (B=64, D=32, T=1024) fp32 -> xbuf[t][b][d] bf16 hi/lo
__global__ void k_xbuf(const float* __restrict__ in,
                       ushort_t* __restrict__ xh, ushort_t* __restrict__ xl) {
    __shared__ float tile[64][65];
    int bp = blockIdx.x >> 4;                    // batch pair 0..31
    int tt = blockIdx.x & 15;                    // t tile 0..15
    int t0 = tt * 64;
    int wv = threadIdx.x >> 6, l = threadIdx.x & 63;
    for (int r = wv * 16; r < wv * 16 + 16; r++) {
        int b = bp * 2 + (r >> 5), d = r & 31;
        tile[r][l] = in[(b * 32 + d) * 1024 + t0 + l];
    }
    __syncthreads();
    for (int i = 0; i < 16; i++) {
        int tl = wv * 16 + i;
        float v = tile[l][tl];
        ushort_t hh = f2bf(v);
        ushort_t ll = f2bf(v - bf2f(hh));
        int o = (t0 + tl) * 2048 + bp * 64 + l;  // = t*64*32 + b*32 + d
        xh[o] = hh;
        xl[o] = ll;
    }
}

// out[b][t] = conv_b + sum_s part[(g*32+s)*16 + bl][t]   (b = g*16+bl)
__global__ void k_reduce(const float* __restrict__ part, float* __restrict__ out,
                         const float* __restrict__ cvb) {
    int b = blockIdx.x >> 2;                     // 0..63
    int t = (blockIdx.x & 3) * 256 + threadIdx.x;
    int g = b >> 4, bl = b & 15;
    const float* p = part + ((size_t)(g * 32 * 16 + bl)) * 1024 + t;
    float sum = 0.f;
    #pragma unroll
    for (int s = 0; s < 32; s++) sum += p[(size_t)s * 16 * 1024];
    out[b * 1024 + t] = sum + cvb[0];
}

// ---------- main recurrent kernel ----------

__global__ __launch_bounds__(NTHR, 1) void k_lstm(
    const ushort_t* __restrict__ wh, const ushort_t* __restrict__ wlo,
    const ushort_t* __restrict__ xh, const ushort_t* __restrict__ xl,
    u64_t* h64hi, u64_t* h64lo, uint_t* flags,
    const float* __restrict__ bih, const float* __restrict__ bhh,
    const float* __restrict__ convw, float* __restrict__ part)
{
    const int tid = threadIdx.x;
    const int w   = tid >> 6;          // wave 0..3 (unit nibble)
    const int l   = tid & 63;
    const int g   = blockIdx.x >> 5;   // batch group 0..3
    const int s   = blockIdx.x & 31;   // hidden slice 0..31 (16 units each)
    const int n   = l & 15;            // B-tile row within wave
    const int q   = l >> 4;            // quad
    const int gtn = n >> 2;            // gate 0..3 (i,f,g,o)
    const int u   = n & 3;             // unit within wave
    const int j   = s * 16 + w * 4 + u;// hidden unit 0..511
    const int row = gtn * HID + j;     // gate row 0..2047
    const int b0  = g * 16;
    const int wg  = s * 4 + w;         // producing-wave id in group, 0..127
    const int rl16 = w * 16 + n;

    __shared__ ushort_t bloF[17 * 4 * 64 * 8]; // W_lo frag-contig: [c][q][rl] 16B
    __shared__ u64_t    hs[4096];              // staged h: plane*2048 + frag idx
    __shared__ float    projsh[4][16][64];     // per-wave projection partials

    // stage W_lo fragment-contiguous: thread (w,l) writes frag (k, q=w, rl=l)
    #pragma unroll
    for (int k = 0; k < 17; k++) {
        int ww = l >> 4, nn = l & 15;
        int rowr = (nn >> 2) * HID + s * 16 + ww * 4 + (nn & 3);
        *(bf16x8*)&bloF[((k * 4 + w) * 64 + l) * 8] =
            *(const bf16x8*)(wlo + rowr * KDIM + k * 32 + w * 8);
    }

    // W_hi fragments in registers: 17 K-chunks
    bf16x8 Bh[17];
    #pragma unroll
    for (int c = 0; c < 17; c++)
        Bh[c] = *(const bf16x8*)(wh + row * KDIM + c * 32 + q * 8);

    const float bias = bih[row] + bhh[row];
    const float cw   = convw[j];
    float cst[4] = {0.f, 0.f, 0.f, 0.f};

    // staging address pieces: global u64 i = k*256+tid -> wgp=k*16+(tid>>4),
    // m=tid&15; c=2k+(hi>>3), q=(hi>>1)&3, d=hi&1 with hi=tid>>4
    const int m16 = tid & 15;
    const int hi4 = tid >> 4;
    const int sq  = (hi4 >> 1) & 3, sd = hi4 & 1, sc0 = hi4 >> 3;

    __syncthreads();

    union frag { u64_t d[2]; bf16x8 v; };

    for (int t = 0; t < T_STEPS; t++) {
        frag Ax, Lx;
        // x fragment: no dependence on flags -> prefetch before poll
        {
            int xo = (t * 64 + b0 + n) * 32 + q * 8;
            Ax.v = *(const bf16x8*)(xh + xo);
            Lx.v = *(const bf16x8*)(xl + xo);
        }

        if (t > 0) {
            // 128 flag lines/group; wave w polls lines w*32+l (l<32), value>=t
            const uint_t* my = flags +
                (size_t)(((((t - 1) & 3) * 4 + g) * 128) + w * 32 + (l & 31)) * 32;
            for (;;) {
                uint_t f = __hip_atomic_load(my, __ATOMIC_RELAXED,
                                             __HIP_MEMORY_SCOPE_AGENT);
                if (__all(l >= 32 || f >= (uint_t)t)) break;
            }
            __syncthreads();
        }

        // stage group h-tile (32 KB, both planes) -> LDS, frag-contig layout
        {
            const u64_t* gh = h64hi + (size_t)(((t & 1) * 4 + g) * 128) * 16;
            const u64_t* gl = h64lo + (size_t)(((t & 1) * 4 + g) * 128) * 16;
            u64_t tmp[16];
            #pragma unroll
            for (int k = 0; k < 8; k++) {
                tmp[k]     = __hip_atomic_load(gh + k * 256 + tid,
                               __ATOMIC_RELAXED, __HIP_MEMORY_SCOPE_AGENT);
                tmp[k + 8] = __hip_atomic_load(gl + k * 256 + tid,
                               __ATOMIC_RELAXED, __HIP_MEMORY_SCOPE_AGENT);
            }
            #pragma unroll
            for (int k = 0; k < 8; k++) {
                int c  = 2 * k + sc0;
                int li = ((c * 4 + sq) * 16 + m16) * 2 + sd;
                hs[li]        = tmp[k];
                hs[li + 2048] = tmp[k + 8];
            }
            __syncthreads();
        }

        // fragments from LDS: contiguous 16B b128 reads, bank-balanced
        frag Ah[16], Al[16];
        #pragma unroll
        for (int c = 0; c < 16; c++) {
            int li = ((c * 4 + q) * 16 + n) * 2;
            Ah[c].v = *(const bf16x8*)&hs[li];
            Al[c].v = *(const bf16x8*)&hs[li + 2048];
        }

        f32x4 a0 = {0,0,0,0}, a1 = {0,0,0,0}, a2 = {0,0,0,0},
              a3 = {0,0,0,0}, a4 = {0,0,0,0}, a5 = {0,0,0,0};
        #pragma unroll
        for (int c = 0; c < 16; c++) {
            bf16x8 bl_ = *(const bf16x8*)&bloF[((c * 4 + q) * 64 + rl16) * 8];
            if (c & 1) {
                a1 = MFMA(Ah[c].v, Bh[c], a1);
                a3 = MFMA(Ah[c].v, bl_,   a3);
                a5 = MFMA(Al[c].v, Bh[c], a5);
            } else {
                a0 = MFMA(Ah[c].v, Bh[c], a0);
                a2 = MFMA(Ah[c].v, bl_,   a2);
                a4 = MFMA(Al[c].v, Bh[c], a4);
            }
        }
        {   // x chunk (c=16)
            bf16x8 bl_ = *(const bf16x8*)&bloF[((16 * 4 + q) * 64 + rl16) * 8];
            a0 = MFMA(Ax.v, Bh[16], a0);
            a2 = MFMA(Ax.v, bl_,    a2);
            a4 = MFMA(Lx.v, Bh[16], a4);
        }
        f32x4 D = (a0 + a1) + (a2 + a3) + (a4 + a5);

        // epilogue: lane holds gate row n for batches m=q*4+r.
        // pack+store interleaved per r so the h stores issue early.
        u64_t* dh = h64hi + (size_t)((((t + 1) & 1) * 4 + g) * 128 + wg) * 16;
        u64_t* dl = h64lo + (size_t)((((t + 1) & 1) * 4 + g) * 128 + wg) * 16;
        float pr[4];
        #pragma unroll
        for (int r = 0; r < 4; r++) {
            float v   = D[r] + bias;
            float act = act_gate(v, gtn == 2);
            float v4  = __shfl_xor(act, 4);
            float v8  = __shfl_xor(act, 8);
            float v12 = __shfl_xor(v4, 8);
            // gate G lives at arr[gtn ^ G]; arr = {act, v4, v8, v12}
            float iv = sel4(gtn,     act, v4, v8, v12);
            float fv = sel4(gtn ^ 1, act, v4, v8, v12);
            float gv = sel4(gtn ^ 2, act, v4, v8, v12);
            float ov = sel4(gtn ^ 3, act, v4, v8, v12);
            float cc = fv * cst[r] + iv * gv;
            cst[r] = cc;
            float th = act_gate(cc, 1);
            float h  = ov * th;
            pr[r] = cw * h;
            ushort_t hb = f2bf(h);
            uint_t hv = (uint_t)hb;
            uint_t lv = (uint_t)f2bf(h - bf2f(hb));
            uint_t h1 = (uint_t)__shfl_xor((int)hv, 1);
            uint_t l1 = (uint_t)__shfl_xor((int)lv, 1);
            uint_t hp = hv | (h1 << 16);          // [u, u^1] valid on even u
            uint_t lp = lv | (l1 << 16);
            uint_t h2 = (uint_t)__shfl_xor((int)hp, 2);
            uint_t l2 = (uint_t)__shfl_xor((int)lp, 2);
            if (n == 0) {
                __hip_atomic_store(dh + q * 4 + r,
                    (u64_t)hp | ((u64_t)h2 << 32),
                    __ATOMIC_RELAXED, __HIP_MEMORY_SCOPE_AGENT);
                __hip_atomic_store(dl + q * 4 + r,
                    (u64_t)lp | ((u64_t)l2 << 32),
                    __ATOMIC_RELAXED, __HIP_MEMORY_SCOPE_AGENT);
            }
        }

        // release: only the 8 h stores outstanding -> one L3 ack, then
        // this wave's own flag line (value t+1, ring t&3).
        __builtin_amdgcn_s_waitcnt(0x0F70);   // vmcnt(0)
        if (l == 0)
            __hip_atomic_store(
                flags + (size_t)(((t & 3) * 4 + g) * 128 + wg) * 32,
                (uint_t)(t + 1),
                __ATOMIC_RELAXED, __HIP_MEMORY_SCOPE_AGENT);

        // projection partial (off critical path): sum this wave's 4 units
        #pragma unroll
        for (int r = 0; r < 4; r++) {
            pr[r] += __shfl_xor(pr[r], 1);
            pr[r] += __shfl_xor(pr[r], 2);
            if (n == 0) projsh[w][q * 4 + r][t & 63] = pr[r];
        }

        // flush projection partials every 64 steps (coalesced NT bursts)
        if ((t & 63) == 63) {
            __syncthreads();
            float* dst = part + (size_t)((g * 32 + s) * 16) * 1024 + (t - 63);
            for (int i = tid; i < 1024; i += NTHR) {
                int b = i >> 6, tl = i & 63;
                float v = (projsh[0][b][tl] + projsh[1][b][tl]) +
                          (projsh[2][b][tl] + projsh[3][b][tl]);
                __builtin_nontemporal_store(v, dst + (size_t)b * 1024 + tl);
            }
            __syncthreads();
        }
    }
}

extern "C" void kernel_launch(void* const* d_in, const int* in_sizes, int n_in,
                              void* d_out, int out_size, void* d_ws, size_t ws_size,
                              hipStream_t stream) {
    const float* in  = (const float*)d_in[0];
    const float* Wih = (const float*)d_in[1];
    const float* Whh = (const float*)d_in[2];
    const float* bih = (const float*)d_in[3];
    const float* bhh = (const float*)d_in[4];
    const float* cvw = (const float*)d_in[5];
    const float* cvb = (const float*)d_in[6];
    float* out = (float*)d_out;

    char* ws = (char*)d_ws;
    ushort_t* wh  = (ushort_t*)ws; ws += (size_t)2048 * KDIM * 2;      // 2,228,224
    ushort_t* wl  = (ushort_t*)ws; ws += (size_t)2048 * KDIM * 2;
    ushort_t* xh  = (ushort_t*)ws; ws += (size_t)1024 * 64 * 32 * 2;   // 4,194,304
    ushort_t* xl  = (ushort_t*)ws; ws += (size_t)1024 * 64 * 32 * 2;
    u64_t*    hhi = (u64_t*)ws;    ws += (size_t)2 * 4 * 128 * 16 * 8; // 131,072
    u64_t*    hlo = (u64_t*)ws;    ws += (size_t)2 * 4 * 128 * 16 * 8;
    uint_t*   fl  = (uint_t*)ws;   ws += (size_t)4 * 4 * 128 * 32 * 4; // 262,144
    float*    pp  = (float*)ws;    ws += (size_t)128 * 16 * 1024 * 4;  // 8,388,608
    // total ~21.8 MB of ws

    k_init<<<256, 256, 0, stream>>>(fl, (uint_t*)hhi, (uint_t*)hlo);
    k_wcat<<<2048, 256, 0, stream>>>(Wih, Whh, wh, wl);
    k_xbuf<<<512, 256, 0, stream>>>(in, xh, xl);
    k_lstm<<<NBLK, NTHR, 0, stream>>>(wh, wl, xh, xl, hhi, hlo, fl,
                                      bih, bhh, cvw, pp);
    k_reduce<<<256, 256, 0, stream>>>(pp, out, cvb);
}